// Round 6
// baseline (220.600 us; speedup 1.0000x reference)
//
#include <hip/hip_runtime.h>

// STU layer: out[b,t,e] = sum_{k,d} phi[t,k] * C[b,t,k,d] * W[k,e,d],
//            C = cumsum_t(phi[t,k] * x[b,t,d])
// Fused: out = A @ WT^T (M=16384, Kdim=4096, N=256); A-tile built in LDS from
// pair-split cumsum chains seeded by chunk-prefix states U. x/U tiles staged
// into LDS via one gload16 per wave (sigma-permuted source -> conflict-free
// reads); B reg-staged (load early, ds_write after BAR1). Single-buffered
// A and B (44KB LDS -> 3 blocks/CU), ks-split=4 (grid 1024).
// B=4, T=4096, D=256, K=16, chunk CH=16.

typedef __bf16 bf16x8 __attribute__((ext_vector_type(8)));
typedef float  f32x4  __attribute__((ext_vector_type(4)));
typedef unsigned short u16;

__device__ static inline u16 f2bf(float f) {          // RNE f32->bf16
    unsigned int u = __float_as_uint(f);
    u = (u + 0x7fffu + ((u >> 16) & 1u)) >> 16;
    return (u16)u;
}

__device__ static inline void gload16(const void* g, void* l) {
    __builtin_amdgcn_global_load_lds((const __attribute__((address_space(1))) void*)g,
                                     (__attribute__((address_space(3))) void*)l, 16, 0, 0);
}

// ---------------- k0: WT[e][d*16+k] = bf16(W[k][e][d]) ----------------
__global__ __launch_bounds__(256) void k0_wt(const float* __restrict__ W, u16* __restrict__ WT) {
    const int e = blockIdx.x, d = threadIdx.x;
    union { u16 u[16]; uint4 v[2]; } ob;
#pragma unroll
    for (int k = 0; k < 16; ++k)
        ob.u[k] = f2bf(W[((size_t)k * 256 + e) * 256 + d]);
    uint4* dst = (uint4*)(WT + (size_t)e * 4096 + d * 16);
    dst[0] = ob.v[0]; dst[1] = ob.v[1];
}

// ---------------- k1: chunk sums U[b,c,d,k] = sum_{s in 16-chunk} phi*x ----------------
__global__ __launch_bounds__(256) void k1_sums(const float* __restrict__ x,
                                               const float* __restrict__ phi,
                                               float* __restrict__ U) {
    __shared__ float phis[256];
    const int tid = threadIdx.x;
    const int b = blockIdx.x, c = blockIdx.y;
    const int t0 = c * 16;
    phis[tid] = phi[t0 * 16 + tid];
    __syncthreads();
    float acc[16];
#pragma unroll
    for (int k = 0; k < 16; ++k) acc[k] = 0.f;
    for (int s = 0; s < 16; ++s) {
        const float xv = x[(size_t)((b << 12) + t0 + s) * 256 + tid];
        union { float f[16]; float4 v[4]; } pv;
#pragma unroll
        for (int j = 0; j < 4; ++j) pv.v[j] = *(const float4*)&phis[s * 16 + j * 4];
#pragma unroll
        for (int k = 0; k < 16; ++k) acc[k] = fmaf(pv.f[k], xv, acc[k]);
    }
    float4* Up = (float4*)(U + ((size_t)((b * 256 + c) * 256 + tid)) * 16);
    union { float f[16]; float4 v[4]; } ov;
#pragma unroll
    for (int k = 0; k < 16; ++k) ov.f[k] = acc[k];
#pragma unroll
    for (int j = 0; j < 4; ++j) Up[j] = ov.v[j];
}

// ---------------- k2: exclusive scan of U over c (in place), 256 chunks ----------------
__global__ __launch_bounds__(64) void k2_scan(float* __restrict__ U) {
    const int b = blockIdx.x;                       // grid (4,64)
    const int dk = blockIdx.y * 64 + threadIdx.x;   // (d*16+k)
    float* base = U + (size_t)b * 1048576 + dk;
    float runv = 0.f;
    for (int g = 0; g < 16; ++g) {
        float v[16];
#pragma unroll
        for (int j = 0; j < 16; ++j) v[j] = base[(size_t)(g * 16 + j) * 4096];
#pragma unroll
        for (int j = 0; j < 16; ++j) {
            const float t = v[j];
            base[(size_t)(g * 16 + j) * 4096] = runv;
            runv += t;
        }
    }
}

// ---------------- k4: fused A-build + GEMM, K-split=4 via atomics ----------------
// BM=64, BN=256, BK=64, 16 K-steps/block. 512 threads = 8 waves.
// LDS 44KB: A 8KB @0 | B 32KB @8192 | xbuf 2x1KB @40960 | ubuf 2x1KB @43008.
// Phase kt: [issue Breg(kt+1); stage xu(kt+2); mfma(kt); BAR1;
//            ds_write B(kt+1); bcomp(kt+1)->A; BAR2]
__global__ __launch_bounds__(512, 6) void k4_fused(const float* __restrict__ x,
                                                   const float* __restrict__ phi,
                                                   const float* __restrict__ U,
                                                   const u16* __restrict__ BT,
                                                   float* __restrict__ C) {
    __shared__ __align__(16) char smem[45056];
    const int tid = threadIdx.x;
    const int m0 = blockIdx.x * 64;              // global row base (bt)
    const int ks = blockIdx.y;                   // kdim quarter 0..3
    const int b  = m0 >> 12, t0 = m0 & 4095, c0 = t0 >> 4;
    const int w = tid >> 6, l = tid & 63;
    const int wm = (w >> 2) * 32, wn = (w & 3) * 64;
    const int lg = l >> 4, lr = l & 15;
    f32x4 acc[2][4] = {};

    // chain mapping: chain=(ch,dl,kl), 2 lanes/chain (sh = s-half)
    const int ch = w & 3, khi = w >> 2;
    const int klo = l & 7, dl = (l >> 3) & 3, sh = l >> 5;
    const int kl = khi * 8 + klo;
    const int row0 = ch * 16 + sh * 8;
    const int colb = (dl * 16 + kl) * 2;

    float p[8];
#pragma unroll
    for (int s = 0; s < 8; ++s) p[s] = phi[(t0 + row0 + s) * 16 + kl];

    // B reg-stage addressing: row = c*64 + (tid>>3); swizzle dep. only on row&7 = (tid>>3)&7
    const int tr = tid >> 3;
    const char* bsrc0 = (const char*)BT + (size_t)tr * 8192 + ks * 2048
                        + (((tid & 7) * 16) ^ ((tr & 7) << 4));
    const int bdst0 = 8192 + tid * 16;

    // xu staging (wave0: x rows sigma-permuted; wave1: U pieces)
    const int sig = ((l & 7) << 3) | (l >> 3);   // involution on 6 bits
    const char* xu_src;
    if (w == 0)      xu_src = (const char*)x + ((size_t)(m0 + sig)) * 1024 + ks * 256;
    else             xu_src = (const char*)U + ((size_t)(b * 256 + c0 + (l >> 4))) * 16384
                              + ks * 4096 + ((l >> 2) & 3) * 64 + (l & 3) * 16;
    const int xu_dst = (w == 0 ? 40960 : 43008) + l * 16;

    auto stage_xu = [&](int kt, int slot) {
        if (w == 0)      gload16(xu_src + kt * 16,  smem + xu_dst + slot * 1024);
        else if (w == 1) gload16(xu_src + kt * 256, smem + xu_dst + slot * 1024);
    };
    uint4 br0, br1, br2, br3;
    auto breg_load = [&](int kt) {
        br0 = *(const uint4*)(bsrc0 + kt * 128);
        br1 = *(const uint4*)(bsrc0 + 524288 + kt * 128);
        br2 = *(const uint4*)(bsrc0 + 1048576 + kt * 128);
        br3 = *(const uint4*)(bsrc0 + 1572864 + kt * 128);
    };
    auto bwrite = [&]() {
        *(uint4*)(smem + bdst0)         = br0;
        *(uint4*)(smem + bdst0 + 8192)  = br1;
        *(uint4*)(smem + bdst0 + 16384) = br2;
        *(uint4*)(smem + bdst0 + 24576) = br3;
    };
    auto bcomp = [&](int kt) {                   // build A-tile for step kt
        const char* xb = smem + 40960 + (kt & 1) * 1024;
        const char* ub = smem + 43008 + (kt & 1) * 1024;
        const float useed = *(const float*)(ub + ch * 256 + dl * 64 + kl * 4);
        float run = sh ? 0.f : useed;
        float ap[8];
#pragma unroll
        for (int s = 0; s < 8; ++s) {
            const float xv = *(const float*)(xb + ((s << 3) | (ch * 2 + sh)) * 16 + dl * 4);
            run = fmaf(p[s], xv, run); ap[s] = run;
        }
        const float cross = __shfl_xor(run, 32, 64);
        const float base = sh ? cross : 0.f;
        char* Ab = smem + row0 * 128;
#pragma unroll
        for (int s = 0; s < 8; ++s)
            *(__bf16*)(Ab + s * 128 + (colb ^ (s << 4))) = (__bf16)(p[s] * (ap[s] + base));
    };
    auto mfma_phase = [&]() {
        const char* Abase = smem;
        const char* Bbase = smem + 8192;
#pragma unroll
        for (int kk = 0; kk < 2; ++kk) {
            const int kb = kk * 64 + lg * 16;
            bf16x8 af[2], bfv[4];
#pragma unroll
            for (int mi = 0; mi < 2; ++mi) {
                const int r = wm + mi * 16 + lr;
                af[mi] = *(const bf16x8*)(Abase + r * 128 + (kb ^ ((r & 7) << 4)));
            }
#pragma unroll
            for (int ni = 0; ni < 4; ++ni) {
                const int n = wn + ni * 16 + lr;
                bfv[ni] = *(const bf16x8*)(Bbase + n * 128 + (kb ^ ((n & 7) << 4)));
            }
#pragma unroll
            for (int mi = 0; mi < 2; ++mi)
#pragma unroll
                for (int ni = 0; ni < 4; ++ni)
                    acc[mi][ni] = __builtin_amdgcn_mfma_f32_16x16x32_bf16(af[mi], bfv[ni], acc[mi][ni], 0, 0, 0);
        }
    };

    // prologue: tile 0 (+ xu for tile 1)
    breg_load(0);
    stage_xu(0, 0);
    stage_xu(1, 1);
    __syncthreads();                 // xu(0,1) landed, br(0) in regs
    bwrite();
    bcomp(0);
    __syncthreads();                 // A(0), B(0) visible

    for (int kt = 0; kt < 16; ++kt) {
        if (kt < 15) breg_load(kt + 1);
        if (kt < 14) stage_xu(kt + 2, kt & 1);
        mfma_phase();
        __syncthreads();             // BAR1: done reading A(kt), B(kt)
        if (kt < 15) {
            bwrite();                // B(kt+1)
            bcomp(kt + 1);           // A(kt+1), reads xu slot (kt+1)&1
            __syncthreads();         // BAR2: writes visible
        }
    }

    // epilogue: four contributions per out element (ks=0..3), commutative f32 adds
#pragma unroll
    for (int mi = 0; mi < 2; ++mi)
#pragma unroll
        for (int ni = 0; ni < 4; ++ni)
#pragma unroll
            for (int r = 0; r < 4; ++r) {
                const int row = m0 + wm + mi * 16 + lg * 4 + r;
                const int col = wn + ni * 16 + lr;
                unsafeAtomicAdd(&C[(size_t)row * 256 + col], acc[mi][ni][r]);
            }
}

extern "C" void kernel_launch(void* const* d_in, const int* in_sizes, int n_in,
                              void* d_out, int out_size, void* d_ws, size_t ws_size,
                              hipStream_t stream) {
    const float* x   = (const float*)d_in[0];   // (4,4096,256)
    const float* W   = (const float*)d_in[1];   // (16,256,256)
    const float* phi = (const float*)d_in[2];   // (4096,16)
    float* out = (float*)d_out;                 // (4,4096,256) f32

    char* ws = (char*)d_ws;
    u16*   WT = (u16*)ws;                       // 2 MB
    float* U  = (float*)(ws + (2u << 20));      // 16 MB

    k0_wt  <<<256, 256, 0, stream>>>(W, WT);
    k1_sums<<<dim3(4, 256), 256, 0, stream>>>(x, phi, U);
    k2_scan<<<dim3(4, 64), 64, 0, stream>>>(U);
    hipMemsetAsync(d_out, 0, (size_t)out_size * sizeof(float), stream);
    k4_fused<<<dim3(256, 4), 512, 0, stream>>>(x, phi, U, WT, out);
}

// Round 7
// 98.703 us; speedup vs baseline: 2.2350x; 2.2350x over previous
//
#include <hip/hip_runtime.h>

// STU layer: out[b,t,e] = sum_{k,d} phi[t,k] * C[b,t,k,d] * W[k,e,d],
//            C = cumsum_t(phi[t,k] * x[b,t,d])
// Fused: out = A @ WT^T (M=16384, Kdim=4096, N=256); the A-tile
// (A[bt, d*16+k] = phi[t,k]*C[b,t,k,d]) is built on the fly in LDS from
// 16-step cumsum chains seeded by chunk-prefix states U. A is never
// materialized in HBM.  (R2 structure — best measured: k4 = 69 us.)
//   WT[e, d*16+k] = W[k,e,d]
// B=4, T=4096, D=256, K=16, chunk CH=16 (256 chunks/batch).

typedef __bf16 bf16x8 __attribute__((ext_vector_type(8)));
typedef float  f32x4  __attribute__((ext_vector_type(4)));
typedef unsigned short u16;

__device__ static inline u16 f2bf(float f) {          // RNE f32->bf16
    unsigned int u = __float_as_uint(f);
    u = (u + 0x7fffu + ((u >> 16) & 1u)) >> 16;
    return (u16)u;
}

__device__ static inline void gload16(const void* g, void* l) {
    __builtin_amdgcn_global_load_lds((const __attribute__((address_space(1))) void*)g,
                                     (__attribute__((address_space(3))) void*)l, 16, 0, 0);
}

// ---------------- k0: WT[e][d*16+k] = bf16(W[k][e][d]) ----------------
__global__ __launch_bounds__(256) void k0_wt(const float* __restrict__ W, u16* __restrict__ WT) {
    const int e = blockIdx.x, d = threadIdx.x;
    union { u16 u[16]; uint4 v[2]; } ob;
#pragma unroll
    for (int k = 0; k < 16; ++k)
        ob.u[k] = f2bf(W[((size_t)k * 256 + e) * 256 + d]);
    uint4* dst = (uint4*)(WT + (size_t)e * 4096 + d * 16);
    dst[0] = ob.v[0]; dst[1] = ob.v[1];
}

// ---------------- k1: chunk sums U[b,c,d,k] = sum_{s in 16-chunk} phi*x ----------------
__global__ __launch_bounds__(256) void k1_sums(const float* __restrict__ x,
                                               const float* __restrict__ phi,
                                               float* __restrict__ U) {
    __shared__ float phis[256];
    const int tid = threadIdx.x;
    const int b = blockIdx.x, c = blockIdx.y;
    const int t0 = c * 16;
    phis[tid] = phi[t0 * 16 + tid];
    __syncthreads();
    float acc[16];
#pragma unroll
    for (int k = 0; k < 16; ++k) acc[k] = 0.f;
    for (int s = 0; s < 16; ++s) {
        const float xv = x[(size_t)((b << 12) + t0 + s) * 256 + tid];
        union { float f[16]; float4 v[4]; } pv;
#pragma unroll
        for (int j = 0; j < 4; ++j) pv.v[j] = *(const float4*)&phis[s * 16 + j * 4];
#pragma unroll
        for (int k = 0; k < 16; ++k) acc[k] = fmaf(pv.f[k], xv, acc[k]);
    }
    float4* Up = (float4*)(U + ((size_t)((b * 256 + c) * 256 + tid)) * 16);
    union { float f[16]; float4 v[4]; } ov;
#pragma unroll
    for (int k = 0; k < 16; ++k) ov.f[k] = acc[k];
#pragma unroll
    for (int j = 0; j < 4; ++j) Up[j] = ov.v[j];
}

// ---------------- k2: exclusive scan of U over c (in place), coalesced ----------------
// U[b][c][dk], dk = d*16+k. Block = (b, 64-dk group); wave lanes cover 64
// consecutive dk at the same c -> 256 B coalesced segments (full granules).
// 4 c-quarters per block combined via 1 KB LDS.
__global__ __launch_bounds__(256) void k2_scan(float* __restrict__ U) {
    const int b  = blockIdx.x;                     // grid (4,64)
    const int dl = threadIdx.x & 63;
    const int dk = blockIdx.y * 64 + dl;
    const int q  = threadIdx.x >> 6;               // c-quarter 0..3
    float* base = U + (size_t)b * 1048576 + (size_t)(q * 64) * 4096 + dk;
    // pass 1: per-quarter sum (loads independent -> pipelined)
    float s = 0.f;
#pragma unroll 8
    for (int j = 0; j < 64; ++j) s += base[(size_t)j * 4096];
    __shared__ float qs[4][64];
    qs[q][dl] = s;
    __syncthreads();
    float pre = 0.f;
#pragma unroll
    for (int i = 0; i < 4; ++i) pre += (i < q) ? qs[i][dl] : 0.f;
    // pass 2: exclusive scan write-back (re-reads are L2/L3-hot)
    float run = pre;
#pragma unroll 8
    for (int j = 0; j < 64; ++j) {
        const float v = base[(size_t)j * 4096];
        base[(size_t)j * 4096] = run;
        run += v;
    }
}

// ---------------- k4: fused A-build + GEMM, K-split=2 via atomics ----------------
// BM=64, BN=256, BK=64; 512 threads = 8 waves. Waves 0-3: build A-tile
// (256 cumsum chains, one per lane). Waves 4-7: stage B via global_load_lds.
// Double-buffered (A 2x8KB, B 2x32KB = 80KB LDS), single barrier per K-step:
// next tile's chains+loads issue BEFORE current MFMA phase.
__global__ __launch_bounds__(512, 4) void k4_fused(const float* __restrict__ x,
                                                   const float* __restrict__ phi,
                                                   const float* __restrict__ U,
                                                   const u16* __restrict__ BT,
                                                   float* __restrict__ C) {
    __shared__ __align__(16) char smem[81920];   // A[2][8192] @0, B[2][32768] @16384
    const int tid = threadIdx.x;
    const int m0 = blockIdx.x * 64;              // global row base (bt)
    const int ks = blockIdx.y;                   // kdim half
    const int b  = m0 >> 12, t0 = m0 & 4095, c0 = t0 >> 4;
    const int w = tid >> 6, l = tid & 63;
    const int wm = (w >> 2) * 32, wn = (w & 3) * 64;
    const int lg = l >> 4, lr = l & 15;
    f32x4 acc[2][4] = {};

    // chain-lane constants (waves 0-3): chain = (chunk=w, d-local=lg, k=lr)
    float p[16];
    if (w < 4) {
#pragma unroll
        for (int s = 0; s < 16; ++s) p[s] = phi[(t0 + w * 16 + s) * 16 + lr];
    }
    const char* Bb = (const char*)BT;
    const int tl = tid & 255;
    const int colb = (lg * 16 + lr) * 2;         // A-tile column byte for chain lane

    auto stageB = [&](int kt, int buf) {         // waves 4-7: 8 x gload16 each
        const int kofs = ks * 4096 + kt * 128;   // byte offset in 8192B WT row
#pragma unroll
        for (int c = 0; c < 8; ++c) {
            const int row = c * 32 + (tl >> 3);
            gload16(Bb + (size_t)row * 8192 + kofs + (((tl & 7) * 16) ^ ((row & 7) << 4)),
                    smem + 16384 + buf * 32768 + c * 4096 + tl * 16);
        }
    };
    auto chains = [&](int kt, int buf) {         // waves 0-3: one 16-step chain
        const int d = ks * 128 + kt * 4 + lg;
        float run = U[(((size_t)(b * 256 + c0 + w)) * 256 + d) * 16 + lr];
        char* Ab = smem + buf * 8192 + w * 2048; // chunk w -> rows w*16..w*16+15
#pragma unroll
        for (int s = 0; s < 16; ++s) {
            const float xv = x[(size_t)(m0 + w * 16 + s) * 256 + d];
            run = fmaf(p[s], xv, run);
            *(u16*)(Ab + s * 128 + (colb ^ ((s & 7) << 4))) = f2bf(p[s] * run);
        }
    };

    // prologue: fill buffer 0
    if (w >= 4) stageB(0, 0); else chains(0, 0);
    __syncthreads();

    for (int kt = 0; kt < 32; ++kt) {
        const int cur = kt & 1;
        if (kt < 31) {                            // issue next tile first
            if (w >= 4) stageB(kt + 1, cur ^ 1);
            else        chains(kt + 1, cur ^ 1);
        }
        const char* Abase = smem + cur * 8192;
        const char* Bbase = smem + 16384 + cur * 32768;
#pragma unroll
        for (int kk = 0; kk < 2; ++kk) {
            const int kb = kk * 64 + lg * 16;
            bf16x8 af[2], bfv[4];
#pragma unroll
            for (int mi = 0; mi < 2; ++mi) {
                const int r = wm + mi * 16 + lr;
                af[mi] = *(const bf16x8*)(Abase + r * 128 + (kb ^ ((r & 7) << 4)));
            }
#pragma unroll
            for (int ni = 0; ni < 4; ++ni) {
                const int n = wn + ni * 16 + lr;
                bfv[ni] = *(const bf16x8*)(Bbase + n * 128 + (kb ^ ((n & 7) << 4)));
            }
#pragma unroll
            for (int mi = 0; mi < 2; ++mi)
#pragma unroll
                for (int ni = 0; ni < 4; ++ni)
                    acc[mi][ni] = __builtin_amdgcn_mfma_f32_16x16x32_bf16(af[mi], bfv[ni], acc[mi][ni], 0, 0, 0);
        }
        __syncthreads();
    }

    // epilogue: two contributions per out element (ks=0/1), commutative f32 adds
#pragma unroll
    for (int mi = 0; mi < 2; ++mi)
#pragma unroll
        for (int ni = 0; ni < 4; ++ni)
#pragma unroll
            for (int r = 0; r < 4; ++r) {
                const int row = m0 + wm + mi * 16 + lg * 4 + r;
                const int col = wn + ni * 16 + lr;
                unsafeAtomicAdd(&C[(size_t)row * 256 + col], acc[mi][ni][r]);
            }
}

extern "C" void kernel_launch(void* const* d_in, const int* in_sizes, int n_in,
                              void* d_out, int out_size, void* d_ws, size_t ws_size,
                              hipStream_t stream) {
    const float* x   = (const float*)d_in[0];   // (4,4096,256)
    const float* W   = (const float*)d_in[1];   // (16,256,256)
    const float* phi = (const float*)d_in[2];   // (4096,16)
    float* out = (float*)d_out;                 // (4,4096,256) f32

    char* ws = (char*)d_ws;
    u16*   WT = (u16*)ws;                       // 2 MB
    float* U  = (float*)(ws + (2u << 20));      // 16 MB

    k0_wt  <<<256, 256, 0, stream>>>(W, WT);
    k1_sums<<<dim3(4, 256), 256, 0, stream>>>(x, phi, U);
    k2_scan<<<dim3(4, 64), 256, 0, stream>>>(U);
    hipMemsetAsync(d_out, 0, (size_t)out_size * sizeof(float), stream);
    k4_fused<<<dim3(256, 2), 512, 0, stream>>>(x, phi, U, WT, out);
}

// Round 8
// 95.436 us; speedup vs baseline: 2.3115x; 1.0342x over previous
//
#include <hip/hip_runtime.h>

// STU layer: out[b,t,e] = sum_{k,d} phi[t,k] * C[b,t,k,d] * W[k,e,d],
//            C = cumsum_t(phi[t,k] * x[b,t,d])
// Fused: out = A @ WT^T (M=16384, Kdim=4096, N=256); A-tile built in LDS from
// cumsum chains seeded by chunk-prefix states U. Deep pipeline (T3/T4/T5):
// B triple-buffered via global_load_lds with counted vmcnt(8) at raw
// s_barrier (loads stay in flight across barriers); x prefetched depth-2
// into registers; A double-buffered. No ks-split -> no atomics, no memset.
// B=4, T=4096, D=256, K=16, chunk CH=16 (256 chunks/batch).

typedef __bf16 bf16x8 __attribute__((ext_vector_type(8)));
typedef float  f32x4  __attribute__((ext_vector_type(4)));
typedef unsigned short u16;
typedef unsigned int   u32;

__device__ static inline u16 f2bf(float f) {          // RNE f32->bf16
    unsigned int u = __float_as_uint(f);
    u = (u + 0x7fffu + ((u >> 16) & 1u)) >> 16;
    return (u16)u;
}

__device__ static inline void gload16(const void* g, void* l) {
    __builtin_amdgcn_global_load_lds((const __attribute__((address_space(1))) void*)g,
                                     (__attribute__((address_space(3))) void*)l, 16, 0, 0);
}

// ---------------- k0: WT[e][d*16+k] = bf16(W[k][e][d]) ----------------
__global__ __launch_bounds__(256) void k0_wt(const float* __restrict__ W, u16* __restrict__ WT) {
    const int e = blockIdx.x, d = threadIdx.x;
    union { u16 u[16]; uint4 v[2]; } ob;
#pragma unroll
    for (int k = 0; k < 16; ++k)
        ob.u[k] = f2bf(W[((size_t)k * 256 + e) * 256 + d]);
    uint4* dst = (uint4*)(WT + (size_t)e * 4096 + d * 16);
    dst[0] = ob.v[0]; dst[1] = ob.v[1];
}

// ---------------- k1: chunk sums U[b,c,d,k] = sum_{s in 16-chunk} phi*x ----------------
__global__ __launch_bounds__(256) void k1_sums(const float* __restrict__ x,
                                               const float* __restrict__ phi,
                                               float* __restrict__ U) {
    __shared__ float phis[256];
    const int tid = threadIdx.x;
    const int b = blockIdx.x, c = blockIdx.y;
    const int t0 = c * 16;
    phis[tid] = phi[t0 * 16 + tid];
    __syncthreads();
    float acc[16];
#pragma unroll
    for (int k = 0; k < 16; ++k) acc[k] = 0.f;
    for (int s = 0; s < 16; ++s) {
        const float xv = x[(size_t)((b << 12) + t0 + s) * 256 + tid];
        union { float f[16]; float4 v[4]; } pv;
#pragma unroll
        for (int j = 0; j < 4; ++j) pv.v[j] = *(const float4*)&phis[s * 16 + j * 4];
#pragma unroll
        for (int k = 0; k < 16; ++k) acc[k] = fmaf(pv.f[k], xv, acc[k]);
    }
    float4* Up = (float4*)(U + ((size_t)((b * 256 + c) * 256 + tid)) * 16);
    union { float f[16]; float4 v[4]; } ov;
#pragma unroll
    for (int k = 0; k < 16; ++k) ov.f[k] = acc[k];
#pragma unroll
    for (int j = 0; j < 4; ++j) Up[j] = ov.v[j];
}

// ---------------- k2: exclusive scan of U over c (in place), coalesced ----------------
__global__ __launch_bounds__(256) void k2_scan(float* __restrict__ U) {
    const int b  = blockIdx.x;                     // grid (4,64)
    const int dl = threadIdx.x & 63;
    const int dk = blockIdx.y * 64 + dl;
    const int q  = threadIdx.x >> 6;               // c-quarter 0..3
    float* base = U + (size_t)b * 1048576 + (size_t)(q * 64) * 4096 + dk;
    float s = 0.f;
#pragma unroll 8
    for (int j = 0; j < 64; ++j) s += base[(size_t)j * 4096];
    __shared__ float qs[4][64];
    qs[q][dl] = s;
    __syncthreads();
    float pre = 0.f;
#pragma unroll
    for (int i = 0; i < 4; ++i) pre += (i < q) ? qs[i][dl] : 0.f;
    float run = pre;
#pragma unroll 8
    for (int j = 0; j < 64; ++j) {
        const float v = base[(size_t)j * 4096];
        base[(size_t)j * 4096] = run;
        run += v;
    }
}

// ---------------- k4: fused A-build + GEMM, deep-pipelined ----------------
// BM=64, BN=256, BK=64, 64 K-steps, 512 thr = 8 waves, 1 block/CU.
// Waves 0-1: chain-build (2 chains/lane, depth 16, b32 packed writes).
// Waves 4-7: B staging (8 gload16 each). All: MFMA.
// LDS 112KB: B[3][32768] @0, A[2][8192] @98304.
__global__ __launch_bounds__(512, 2) void k4_fused(const float* __restrict__ x,
                                                   const float* __restrict__ phi,
                                                   const float* __restrict__ U,
                                                   const u16* __restrict__ BT,
                                                   float* __restrict__ C) {
    __shared__ __align__(16) char smem[114688];
    const int tid = threadIdx.x;
    const int m0 = blockIdx.x * 64;              // global row base (bt)
    const int b  = m0 >> 12, t0 = m0 & 4095, c0 = t0 >> 4;
    const int w = tid >> 6, l = tid & 63;
    const int wm = (w >> 2) * 32, wn = (w & 3) * 64;
    const int lg = l >> 4, lr = l & 15;
    f32x4 acc[2][4] = {};

    const bool is_chain = (w < 2);
    const bool is_stage = (w >= 4);

    // chain lane mapping: lane owns chains (ch, dl, k=2kp & 2kp+1), depth 16
    const int kp = l & 7, dl = (l >> 3) & 3, ch = ((w & 1) << 1) | (l >> 5);
    const int colb = dl * 32 + kp * 4;           // A col byte (elem dl*16+2kp)
    float2 p01[16];
    if (is_chain) {
#pragma unroll
        for (int s = 0; s < 16; ++s)
            p01[s] = *(const float2*)&phi[(t0 + ch * 16 + s) * 16 + kp * 2];
    }

    // stage addressing (waves 4-7): row = c*32 + (tl>>3)
    const int tl = tid & 255;
    const char* bsrc = (const char*)BT + (size_t)(tl >> 3) * 8192
                     + (((tl & 7) * 16) ^ (((tl >> 3) & 7) << 4));
    char* const smemA = smem + 98304;

    auto stageB = [&](int kt, int bufw) {
        char* dst = smem + bufw * 32768 + tl * 16;
        const char* src = bsrc + (size_t)kt * 128;
#pragma unroll
        for (int c = 0; c < 8; ++c)
            gload16(src + (size_t)c * 262144, dst + c * 4096);
    };
    auto issueX = [&](float (&xr)[16], float2& us, int kt) {
        const int d = kt * 4 + dl;
        const float* xp = x + (size_t)(m0 + ch * 16) * 256 + d;
#pragma unroll
        for (int s = 0; s < 16; ++s) xr[s] = xp[(size_t)s * 256];
        us = *(const float2*)&U[((size_t)((b * 256 + c0 + ch) * 256 + d)) * 16 + kp * 2];
    };
    auto chains = [&](const float (&xr)[16], float2 us, int abw) {
        float r0 = us.x, r1 = us.y;
        char* Ab = smemA + abw * 8192 + ch * 2048;
#pragma unroll
        for (int s = 0; s < 16; ++s) {
            r0 = fmaf(p01[s].x, xr[s], r0);
            r1 = fmaf(p01[s].y, xr[s], r1);
            const float v0 = p01[s].x * r0, v1 = p01[s].y * r1;
            u32 pk;
            asm("v_cvt_pk_bf16_f32 %0, %1, %2" : "=v"(pk) : "v"(v0), "v"(v1));
            *(u32*)(Ab + s * 128 + (colb ^ ((s & 7) << 4))) = pk;
        }
    };
    auto mfma_phase = [&](int abr, int bbr) {
        const char* Abase = smemA + abr * 8192;
        const char* Bbase = smem + bbr * 32768;
#pragma unroll
        for (int kk = 0; kk < 2; ++kk) {
            const int kb = kk * 64 + lg * 16;
            bf16x8 af[2], bfv[4];
#pragma unroll
            for (int mi = 0; mi < 2; ++mi) {
                const int r = wm + mi * 16 + lr;
                af[mi] = *(const bf16x8*)(Abase + r * 128 + (kb ^ ((r & 7) << 4)));
            }
#pragma unroll
            for (int ni = 0; ni < 4; ++ni) {
                const int n = wn + ni * 16 + lr;
                bfv[ni] = *(const bf16x8*)(Bbase + n * 128 + (kb ^ ((n & 7) << 4)));
            }
#pragma unroll
            for (int mi = 0; mi < 2; ++mi)
#pragma unroll
                for (int ni = 0; ni < 4; ++ni)
                    acc[mi][ni] = __builtin_amdgcn_mfma_f32_16x16x32_bf16(af[mi], bfv[ni], acc[mi][ni], 0, 0, 0);
        }
    };

    // ---- prologue: B(0)->buf0, B(1)->buf1 in flight; x(0),x(1) in regs; A(0)
    float xA[16], xB[16]; float2 uA, uB;
    if (is_chain) { issueX(xA, uA, 0); issueX(xB, uB, 1); }
    if (is_stage) { stageB(0, 0); stageB(1, 1); }
    __builtin_amdgcn_sched_barrier(0);
    if (is_chain) {
        chains(xA, uA, 0);                       // compiler-inserted vmcnt for xA
        asm volatile("s_waitcnt lgkmcnt(0)" ::: "memory");
    }
    if (is_stage) asm volatile("s_waitcnt vmcnt(8)" ::: "memory");  // B(0) done
    asm volatile("s_barrier" ::: "memory");

    int br = 0, bw = 2;
    // per-step: issue(kt+2) | chains(kt+1) | MFMA(kt) | counted waits | barrier
    auto body = [&](int kt, float (&xW)[16], float2& uW,
                    const float (&xR)[16], float2 uR) {
        const int abr = kt & 1;
        if (kt + 2 < 64) {
            if (is_stage)      stageB(kt + 2, bw);
            else if (is_chain) issueX(xW, uW, kt + 2);
        }
        __builtin_amdgcn_sched_barrier(0);
        if (is_chain && (kt + 1 < 64)) chains(xR, uR, abr ^ 1);
        __builtin_amdgcn_s_setprio(1);
        mfma_phase(abr, br);
        __builtin_amdgcn_s_setprio(0);
        if (is_chain) asm volatile("s_waitcnt lgkmcnt(0)" ::: "memory");
        if (is_stage) {
            if (kt + 2 < 64) asm volatile("s_waitcnt vmcnt(8)" ::: "memory");
            else             asm volatile("s_waitcnt vmcnt(0)" ::: "memory");
        }
        if (kt < 63) asm volatile("s_barrier" ::: "memory");
        br = (br == 2) ? 0 : br + 1;
        bw = (bw == 2) ? 0 : bw + 1;
    };

    for (int kt = 0; kt < 64; kt += 2) {
        body(kt,     xA, uA, xB, uB);            // even: write xA, read xB
        body(kt + 1, xB, uB, xA, uA);            // odd : write xB, read xA
    }

    // ---- epilogue: direct stores (single contribution per element)
#pragma unroll
    for (int mi = 0; mi < 2; ++mi)
#pragma unroll
        for (int ni = 0; ni < 4; ++ni)
#pragma unroll
            for (int r = 0; r < 4; ++r) {
                const int row = m0 + wm + mi * 16 + lg * 4 + r;
                const int col = wn + ni * 16 + lr;
                C[(size_t)row * 256 + col] = acc[mi][ni][r];
            }
}

extern "C" void kernel_launch(void* const* d_in, const int* in_sizes, int n_in,
                              void* d_out, int out_size, void* d_ws, size_t ws_size,
                              hipStream_t stream) {
    const float* x   = (const float*)d_in[0];   // (4,4096,256)
    const float* W   = (const float*)d_in[1];   // (16,256,256)
    const float* phi = (const float*)d_in[2];   // (4096,16)
    float* out = (float*)d_out;                 // (4,4096,256) f32

    char* ws = (char*)d_ws;
    u16*   WT = (u16*)ws;                       // 2 MB
    float* U  = (float*)(ws + (2u << 20));      // 16 MB

    k0_wt  <<<256, 256, 0, stream>>>(W, WT);
    k1_sums<<<dim3(4, 256), 256, 0, stream>>>(x, phi, U);
    k2_scan<<<dim3(4, 64), 256, 0, stream>>>(U);
    k4_fused<<<256, 512, 0, stream>>>(x, phi, U, WT, out);
}